// Round 2
// baseline (275.652 us; speedup 1.0000x reference)
//
#include <hip/hip_runtime.h>

// Problem constants: B=4, N=2048, F=D=128, H=4.
#define NB 4
#define NN 2048
#define ND 128
#define NH 4

typedef short short8 __attribute__((ext_vector_type(8)));
typedef short short4v __attribute__((ext_vector_type(4)));
typedef float floatx4 __attribute__((ext_vector_type(4)));

__device__ __forceinline__ short f2bf(float f){
  unsigned u = __float_as_uint(f);
  u += 0x7FFFu + ((u >> 16) & 1u);   // round-to-nearest-even
  return (short)(u >> 16);
}
__device__ __forceinline__ float bf2f(short s){
  unsigned u = ((unsigned)(unsigned short)s) << 16;
  return __uint_as_float(u);
}

// ---------------- K0: WT[d][f] = W[f][d]; attnT[h][e][d] = attn[h][d][e] (bf16) ----
__global__ void k0_transpose(const float* __restrict__ W, const float* __restrict__ attn,
                             short* __restrict__ WT, short* __restrict__ attnT){
  int mat = blockIdx.x;                       // 0 = W, 1..4 = attn heads
  const float* src = (mat == 0) ? W : (attn + (mat - 1) * 16384);
  short* dst = (mat == 0) ? WT : (attnT + (mat - 1) * 16384);
  __shared__ short tile[128 * 130];
  int t = threadIdx.x;
  for (int k = 0; k < 64; ++k){               // coalesced read, transposed LDS write
    int idx = k * 256 + t;
    int r = idx >> 7, c = idx & 127;
    tile[c * 130 + r] = f2bf(src[idx]);
  }
  __syncthreads();
  for (int k = 0; k < 8; ++k){                // coalesced vector-ish write out
    int g = k * 256 + t;
    int r = g >> 4, c8 = g & 15;
    short8 v;
    #pragma unroll
    for (int j = 0; j < 8; ++j) v[j] = tile[r * 130 + c8 * 8 + j];
    *(short8*)&dst[r * 128 + c8 * 8] = v;
  }
}

// ---------------- K1: Xp = X @ W + bias  (bf16 out), MFMA gemm_bt vs WT -----------
__global__ __launch_bounds__(256) void k1_xp(const float* __restrict__ X,
                                             const short* __restrict__ WT,
                                             const float* __restrict__ bias,
                                             short* __restrict__ Xp){
  int bid = blockIdx.x;                       // 128 = 4b * 32 i-tiles
  int b = bid >> 5, i0 = (bid & 31) << 6;
  int t = threadIdx.x, w = t >> 6, lane = t & 63, lq = lane >> 4, lc = lane & 15;
  __shared__ __align__(16) short ldsB[16384]; // swizzled [16 fblk][128 d][8]
  #pragma unroll
  for (int c = 0; c < 8; ++c){
    int q = c * 256 + t; int fblk = q >> 7; int d = q & 127;
    *(short8*)&ldsB[q * 8] = *(const short8*)&WT[d * 128 + fblk * 8];
  }
  short8 af[4][4];
  #pragma unroll
  for (int ib = 0; ib < 4; ++ib)
    #pragma unroll
    for (int k = 0; k < 4; ++k){
      const float* xp = &X[(b * NN + i0 + ib * 16 + lc) * ND + k * 32 + lq * 8];
      float4 x0 = *(const float4*)xp;
      float4 x1 = *(const float4*)(xp + 4);
      short8 s;
      s[0]=f2bf(x0.x); s[1]=f2bf(x0.y); s[2]=f2bf(x0.z); s[3]=f2bf(x0.w);
      s[4]=f2bf(x1.x); s[5]=f2bf(x1.y); s[6]=f2bf(x1.z); s[7]=f2bf(x1.w);
      af[ib][k] = s;
    }
  __syncthreads();
  floatx4 acc[4][2];
  #pragma unroll
  for (int ib = 0; ib < 4; ++ib)
    #pragma unroll
    for (int eb = 0; eb < 2; ++eb) acc[ib][eb] = (floatx4){0.f, 0.f, 0.f, 0.f};
  #pragma unroll
  for (int eb = 0; eb < 2; ++eb)
    #pragma unroll
    for (int k = 0; k < 4; ++k){
      short8 bf = *(short8*)&ldsB[(k * 4 + lq) * 1024 + (w * 32 + eb * 16 + lc) * 8];
      #pragma unroll
      for (int ib = 0; ib < 4; ++ib)
        acc[ib][eb] = __builtin_amdgcn_mfma_f32_16x16x32_bf16(af[ib][k], bf, acc[ib][eb], 0, 0, 0);
    }
  #pragma unroll
  for (int ib = 0; ib < 4; ++ib)
    #pragma unroll
    for (int eb = 0; eb < 2; ++eb){
      int d = w * 32 + eb * 16 + lc;
      float bv = bias[d];
      #pragma unroll
      for (int r = 0; r < 4; ++r){
        int n = i0 + ib * 16 + lq * 4 + r;
        Xp[(b * NN + n) * ND + d] = f2bf(acc[ib][eb][r] + bv);
      }
    }
}

// ---------------- K1b: XpT[b][d][n] = Xp[b][n][d] (bf16, vectorized) ---------------
__global__ void k1b_transpose(const short* __restrict__ Xp, short* __restrict__ XpT){
  int bid = blockIdx.x;                       // 256 = 4b * 32 ntiles * 2 dtiles
  int b = bid >> 6; int rem = bid & 63;
  int n0 = (rem >> 1) << 6, d0 = (rem & 1) << 6;
  __shared__ short tile[64 * 66];             // [d][n], pad 66
  int t = threadIdx.x;
  #pragma unroll
  for (int c = 0; c < 2; ++c){
    int g = c * 256 + t; int r = g >> 3, c8 = g & 7;
    short8 v = *(const short8*)&Xp[(b * NN + n0 + r) * ND + d0 + c8 * 8];
    #pragma unroll
    for (int j = 0; j < 8; ++j) tile[(c8 * 8 + j) * 66 + r] = v[j];
  }
  __syncthreads();
  #pragma unroll
  for (int c = 0; c < 2; ++c){
    int g = c * 256 + t; int d = g >> 3, n8 = g & 7;
    short8 v;
    #pragma unroll
    for (int j = 0; j < 8; ++j) v[j] = tile[d * 66 + n8 * 8 + j];
    *(short8*)&XpT[(b * ND + d0 + d) * NN + n0 + n8 * 8] = v;
  }
}

// ---------------- K2: Y[b][h] = Xp @ attn_h  (bf16 out), MFMA vs attnT ------------
__global__ __launch_bounds__(256) void k2_y(const short* __restrict__ Xp,
                                            const short* __restrict__ attnT,
                                            short* __restrict__ Y){
  int bid = blockIdx.x;                       // 512 = 4b * 4h * 32
  int it = bid & 31, h = (bid >> 5) & 3, b = bid >> 7;
  int i0 = it << 6;
  int t = threadIdx.x, w = t >> 6, lane = t & 63, lq = lane >> 4, lc = lane & 15;
  __shared__ __align__(16) short ldsB[16384]; // swizzled [16 dblk][128 e][8]
  const short* Bsrc = attnT + h * 16384;
  #pragma unroll
  for (int c = 0; c < 8; ++c){
    int q = c * 256 + t; int dblk = q >> 7; int e = q & 127;
    *(short8*)&ldsB[q * 8] = *(const short8*)&Bsrc[e * 128 + dblk * 8];
  }
  short8 af[4][4];
  #pragma unroll
  for (int ib = 0; ib < 4; ++ib)
    #pragma unroll
    for (int k = 0; k < 4; ++k)
      af[ib][k] = *(const short8*)&Xp[(b * NN + i0 + ib * 16 + lc) * ND + k * 32 + lq * 8];
  __syncthreads();
  floatx4 acc[4][2];
  #pragma unroll
  for (int ib = 0; ib < 4; ++ib)
    #pragma unroll
    for (int eb = 0; eb < 2; ++eb) acc[ib][eb] = (floatx4){0.f, 0.f, 0.f, 0.f};
  #pragma unroll
  for (int eb = 0; eb < 2; ++eb)
    #pragma unroll
    for (int k = 0; k < 4; ++k){
      short8 bf = *(short8*)&ldsB[(k * 4 + lq) * 1024 + (w * 32 + eb * 16 + lc) * 8];
      #pragma unroll
      for (int ib = 0; ib < 4; ++ib)
        acc[ib][eb] = __builtin_amdgcn_mfma_f32_16x16x32_bf16(af[ib][k], bf, acc[ib][eb], 0, 0, 0);
    }
  #pragma unroll
  for (int ib = 0; ib < 4; ++ib)
    #pragma unroll
    for (int eb = 0; eb < 2; ++eb){
      int e = w * 32 + eb * 16 + lc;
      #pragma unroll
      for (int r = 0; r < 4; ++r){
        int n = i0 + ib * 16 + lq * 4 + r;
        Y[((b * NH + h) * NN + n) * ND + e] = f2bf(acc[ib][eb][r]);
      }
    }
}

// ---------------- K3 v3: barrier-free fused kernel --------------------------------
// Key identity: S^T MFMA output layout (lane: S[m=lq*4+r][i=lc]) IS the A-fragment
// layout of v_mfma_f32_16x16x16_bf16 (lane: A[row=lc -> i][k=lq*4+j -> m]). So each
// wave feeds its own tanh'd P straight into PV in-register: no cross-wave exchange,
// no LDS P buffer, NO barrier in the main loop. Each wave owns 16 m-rows/iter and a
// private acc[16 i][128 d]; the 4 waves sum once through LDS at the end.
// Y (16KB) staged once in LDS, XOR-swizzled -> conflict-free ds_read_b128, and no
// 64-VGPR yf pinning (v2's compiler rematerialized yf from global per use!).
// grid 2048 = (ms 4, b 4, 128 i-tiles of 16 rows); m-range = ms*512..+512.
__global__ __launch_bounds__(256, 4) void k3_fused(const short* __restrict__ Xp,
                                                   const short* __restrict__ XpT,
                                                   const short* __restrict__ Y,
                                                   const float* __restrict__ A,
                                                   float* __restrict__ part){
  int bid = blockIdx.x;
  int it = bid & 127, b = (bid >> 7) & 3, ms = bid >> 9;
  int i0 = it << 4;
  int t = threadIdx.x, w = t >> 6, lane = t & 63, lq = lane >> 4, lc = lane & 15;

  // 32KB: ldsY (16KB, swizzled bf16) during the loop; red (32KB f32) at epilogue.
  __shared__ __align__(16) char smem[32768];

  // stage Y[b][4h][i0..i0+16][128] -> LDS, XOR-swizzle 16B slot with (i&7)
  #pragma unroll
  for (int c = 0; c < 4; ++c){
    int slot = c * 256 + t;
    int h = slot >> 8, i = (slot >> 4) & 15, d8 = slot & 15;
    short8 v = *(const short8*)&Y[((b * NH + h) * NN + i0 + i) * ND + d8 * 8];
    *(short8*)(smem + h * 4096 + i * 256 + ((d8 ^ (i & 7)) << 4)) = v;
  }
  __syncthreads();                            // the only pre-epilogue barrier

  floatx4 acc[8];                             // acc[dt] = part[i=lq*4+r][d=dt*16+lc]
  #pragma unroll
  for (int dt = 0; dt < 8; ++dt) acc[dt] = (floatx4){0.f,0.f,0.f,0.f};

  const int mbase = ms << 9;                  // 512 m per block, 128 per wave
  const float* arow = &A[(size_t)(b * NN + i0 + lc) * NN];

  // adjacency prefetch for itn=0 (this wave's 16 m-rows at row i0+lc)
  floatx4 av = *(const floatx4*)&arow[mbase + w * 16 + lq * 4];

  for (int itn = 0; itn < 8; ++itn){
    int m0 = mbase + itn * 64 + w * 16;       // this wave's 16 m-rows

    // S^T A-frags: Xp rows m0..m0+15 (L2/L3-resident)
    short8 xpf[4];
    const short* xr = Xp + (b * NN + m0 + lc) * ND;
    #pragma unroll
    for (int k = 0; k < 4; ++k) xpf[k] = *(const short8*)&xr[k * 32 + lq * 8];

    // PV B-frags: XpT[d][m0..m0+15], lane holds B[k=lq*4+j][col=d=dt*16+lc] (8B)
    short4v xt[8];
    #pragma unroll
    for (int dt = 0; dt < 8; ++dt)
      xt[dt] = *(const short4v*)&XpT[(size_t)(b * ND + dt * 16 + lc) * NN + m0 + lq * 4];

    // next-iter adjacency (HBM ~900cy, hides under S^T+tanh+PV; never drained)
    floatx4 avn = av;
    if (itn < 7) avn = *(const floatx4*)&arow[m0 + 64 + lq * 4];

    // S^T per head (Y B-frags from swizzled LDS), tanh, head-mean in-register
    float psum[4] = {0.f, 0.f, 0.f, 0.f};
    #pragma unroll
    for (int h = 0; h < 4; ++h){
      floatx4 S = (floatx4){0.f,0.f,0.f,0.f};
      #pragma unroll
      for (int k = 0; k < 4; ++k){
        short8 yf = *(short8*)(smem + h * 4096 + lc * 256 + (((k * 4 + lq) ^ (lc & 7)) << 4));
        S = __builtin_amdgcn_mfma_f32_16x16x32_bf16(xpf[k], yf, S, 0, 0, 0);
      }
      #pragma unroll
      for (int r = 0; r < 4; ++r){
        float x = av[r] * S[r];
        float e = __builtin_amdgcn_exp2f(x * 2.885390081777926f);  // e^{2x}
        psum[r] += 1.f - 2.f * __builtin_amdgcn_rcpf(e + 1.f);     // tanh
      }
    }

    // P -> bf16 hi/lo split; p[r] IS the K=16 A-frag element j=r directly
    short4v hi4, lo4;
    #pragma unroll
    for (int r = 0; r < 4; ++r){
      float pb = 0.25f * psum[r];
      short h16 = f2bf(pb);
      hi4[r] = h16;
      lo4[r] = f2bf(pb - bf2f(h16));
    }

    // PV: acc[dt] += (Phi + Plo) @ Xp over this wave's 16 m (K=16 MFMA, in-register)
    #pragma unroll
    for (int dt = 0; dt < 8; ++dt){
      acc[dt] = __builtin_amdgcn_mfma_f32_16x16x16bf16_1k(hi4, xt[dt], acc[dt], 0, 0, 0);
      acc[dt] = __builtin_amdgcn_mfma_f32_16x16x16bf16_1k(lo4, xt[dt], acc[dt], 0, 0, 0);
    }
    av = avn;
  }

  // epilogue: cross-wave sum via LDS (overlay red on ldsY region), single pass
  __syncthreads();                            // all waves done reading ldsY
  float* red = (float*)smem;                  // red[w][i][d] = w*2048 + i*128 + d
  #pragma unroll
  for (int dt = 0; dt < 8; ++dt)
    #pragma unroll
    for (int r = 0; r < 4; ++r)
      red[w * 2048 + (lq * 4 + r) * 128 + dt * 16 + lc] = acc[dt][r];
  __syncthreads();
  float* dst = part + (size_t)ms * 1048576 + (size_t)(b * NN + i0) * ND;
  #pragma unroll
  for (int j = 0; j < 8; ++j){
    int idx = j * 256 + t;                    // idx = i*128 + d, coalesced
    dst[idx] = red[idx] + red[2048 + idx] + red[4096 + idx] + red[6144 + idx];
  }
}

// ---------------- K4: out = relu(relu(Σ ms-partials) + X) -------------------------
__global__ void k4_final(const float* __restrict__ part, const float* __restrict__ X,
                         float* __restrict__ out){
  int f = (blockIdx.x * 256 + threadIdx.x) * 4;
  float4 s0 = *(const float4*)(part + f);
  float4 s1 = *(const float4*)(part + 1048576 + f);
  float4 s2 = *(const float4*)(part + 2097152 + f);
  float4 s3 = *(const float4*)(part + 3145728 + f);
  float4 xv = *(const float4*)(X + f);
  float4 o;
  o.x = fmaxf(fmaxf(s0.x + s1.x + s2.x + s3.x, 0.f) + xv.x, 0.f);
  o.y = fmaxf(fmaxf(s0.y + s1.y + s2.y + s3.y, 0.f) + xv.y, 0.f);
  o.z = fmaxf(fmaxf(s0.z + s1.z + s2.z + s3.z, 0.f) + xv.z, 0.f);
  o.w = fmaxf(fmaxf(s0.w + s1.w + s2.w + s3.w, 0.f) + xv.w, 0.f);
  *(float4*)(out + f) = o;
}

// ---------------- launch ----------------------------------------------------------
extern "C" void kernel_launch(void* const* d_in, const int* in_sizes, int n_in,
                              void* d_out, int out_size, void* d_ws, size_t ws_size,
                              hipStream_t stream) {
  const float* X    = (const float*)d_in[0];   // [4,2048,128]
  const float* A    = (const float*)d_in[1];   // [4,2048,2048]
  const float* W    = (const float*)d_in[2];   // [128,128]
  const float* bias = (const float*)d_in[3];   // [128]
  const float* attn = (const float*)d_in[4];   // [4,128,128]
  float* out = (float*)d_out;

  // workspace layout
  const size_t OFF_XP    = 0;                          // 2 MB bf16
  const size_t OFF_XPT   = (size_t)2 << 20;            // 2 MB bf16
  const size_t OFF_Y     = (size_t)4 << 20;            // 8 MB bf16
  const size_t OFF_PART  = (size_t)12 << 20;           // 16 MB f32 (4 partials)
  const size_t OFF_WT    = (size_t)28 << 20;           // 32 KB bf16
  const size_t OFF_ATTNT = OFF_WT + 32768;             // 128 KB bf16
  const size_t NEED = OFF_ATTNT + 131072;
  if (ws_size < NEED) return;

  char* ws = (char*)d_ws;
  short* Xp    = (short*)(ws + OFF_XP);
  short* XpT   = (short*)(ws + OFF_XPT);
  short* Y     = (short*)(ws + OFF_Y);
  float* part  = (float*)(ws + OFF_PART);
  short* WT    = (short*)(ws + OFF_WT);
  short* attnT = (short*)(ws + OFF_ATTNT);

  k0_transpose<<<5, 256, 0, stream>>>(W, attn, WT, attnT);
  k1_xp<<<128, 256, 0, stream>>>(X, WT, bias, Xp);
  k1b_transpose<<<256, 256, 0, stream>>>(Xp, XpT);
  k2_y<<<512, 256, 0, stream>>>(Xp, attnT, Y);
  k3_fused<<<2048, 256, 0, stream>>>(Xp, XpT, Y, A, part);
  k4_final<<<1024, 256, 0, stream>>>(part, X, out);
}

// Round 3
// 226.873 us; speedup vs baseline: 1.2150x; 1.2150x over previous
//
#include <hip/hip_runtime.h>

// Problem constants: B=4, N=2048, F=D=128, H=4.
#define NB 4
#define NN 2048
#define ND 128
#define NH 4

typedef short short8 __attribute__((ext_vector_type(8)));
typedef short short4v __attribute__((ext_vector_type(4)));
typedef float floatx4 __attribute__((ext_vector_type(4)));

__device__ __forceinline__ short f2bf(float f){
  unsigned u = __float_as_uint(f);
  u += 0x7FFFu + ((u >> 16) & 1u);   // round-to-nearest-even
  return (short)(u >> 16);
}
__device__ __forceinline__ float bf2f(short s){
  unsigned u = ((unsigned)(unsigned short)s) << 16;
  return __uint_as_float(u);
}

// ---------------- K0: WT[d][f] = W[f][d]; attnT[h][e][d] = attn[h][d][e] (bf16) ----
__global__ void k0_transpose(const float* __restrict__ W, const float* __restrict__ attn,
                             short* __restrict__ WT, short* __restrict__ attnT){
  int mat = blockIdx.x;                       // 0 = W, 1..4 = attn heads
  const float* src = (mat == 0) ? W : (attn + (mat - 1) * 16384);
  short* dst = (mat == 0) ? WT : (attnT + (mat - 1) * 16384);
  __shared__ short tile[128 * 130];
  int t = threadIdx.x;
  for (int k = 0; k < 64; ++k){               // coalesced read, transposed LDS write
    int idx = k * 256 + t;
    int r = idx >> 7, c = idx & 127;
    tile[c * 130 + r] = f2bf(src[idx]);
  }
  __syncthreads();
  for (int k = 0; k < 8; ++k){                // coalesced vector-ish write out
    int g = k * 256 + t;
    int r = g >> 4, c8 = g & 15;
    short8 v;
    #pragma unroll
    for (int j = 0; j < 8; ++j) v[j] = tile[r * 130 + c8 * 8 + j];
    *(short8*)&dst[r * 128 + c8 * 8] = v;
  }
}

// ---------------- K1: Xp = X @ W + bias  (bf16 out), MFMA gemm_bt vs WT -----------
__global__ __launch_bounds__(256) void k1_xp(const float* __restrict__ X,
                                             const short* __restrict__ WT,
                                             const float* __restrict__ bias,
                                             short* __restrict__ Xp){
  int bid = blockIdx.x;                       // 128 = 4b * 32 i-tiles
  int b = bid >> 5, i0 = (bid & 31) << 6;
  int t = threadIdx.x, w = t >> 6, lane = t & 63, lq = lane >> 4, lc = lane & 15;
  __shared__ __align__(16) short ldsB[16384]; // swizzled [16 fblk][128 d][8]
  #pragma unroll
  for (int c = 0; c < 8; ++c){
    int q = c * 256 + t; int fblk = q >> 7; int d = q & 127;
    *(short8*)&ldsB[q * 8] = *(const short8*)&WT[d * 128 + fblk * 8];
  }
  short8 af[4][4];
  #pragma unroll
  for (int ib = 0; ib < 4; ++ib)
    #pragma unroll
    for (int k = 0; k < 4; ++k){
      const float* xp = &X[(b * NN + i0 + ib * 16 + lc) * ND + k * 32 + lq * 8];
      float4 x0 = *(const float4*)xp;
      float4 x1 = *(const float4*)(xp + 4);
      short8 s;
      s[0]=f2bf(x0.x); s[1]=f2bf(x0.y); s[2]=f2bf(x0.z); s[3]=f2bf(x0.w);
      s[4]=f2bf(x1.x); s[5]=f2bf(x1.y); s[6]=f2bf(x1.z); s[7]=f2bf(x1.w);
      af[ib][k] = s;
    }
  __syncthreads();
  floatx4 acc[4][2];
  #pragma unroll
  for (int ib = 0; ib < 4; ++ib)
    #pragma unroll
    for (int eb = 0; eb < 2; ++eb) acc[ib][eb] = (floatx4){0.f, 0.f, 0.f, 0.f};
  #pragma unroll
  for (int eb = 0; eb < 2; ++eb)
    #pragma unroll
    for (int k = 0; k < 4; ++k){
      short8 bf = *(short8*)&ldsB[(k * 4 + lq) * 1024 + (w * 32 + eb * 16 + lc) * 8];
      #pragma unroll
      for (int ib = 0; ib < 4; ++ib)
        acc[ib][eb] = __builtin_amdgcn_mfma_f32_16x16x32_bf16(af[ib][k], bf, acc[ib][eb], 0, 0, 0);
    }
  #pragma unroll
  for (int ib = 0; ib < 4; ++ib)
    #pragma unroll
    for (int eb = 0; eb < 2; ++eb){
      int d = w * 32 + eb * 16 + lc;
      float bv = bias[d];
      #pragma unroll
      for (int r = 0; r < 4; ++r){
        int n = i0 + ib * 16 + lq * 4 + r;
        Xp[(b * NN + n) * ND + d] = f2bf(acc[ib][eb][r] + bv);
      }
    }
}

// ---------------- K1b: XpT[b][d][n] = Xp[b][n][d] (bf16, vectorized) ---------------
__global__ void k1b_transpose(const short* __restrict__ Xp, short* __restrict__ XpT){
  int bid = blockIdx.x;                       // 256 = 4b * 32 ntiles * 2 dtiles
  int b = bid >> 6; int rem = bid & 63;
  int n0 = (rem >> 1) << 6, d0 = (rem & 1) << 6;
  __shared__ short tile[64 * 66];             // [d][n], pad 66
  int t = threadIdx.x;
  #pragma unroll
  for (int c = 0; c < 2; ++c){
    int g = c * 256 + t; int r = g >> 3, c8 = g & 7;
    short8 v = *(const short8*)&Xp[(b * NN + n0 + r) * ND + d0 + c8 * 8];
    #pragma unroll
    for (int j = 0; j < 8; ++j) tile[(c8 * 8 + j) * 66 + r] = v[j];
  }
  __syncthreads();
  #pragma unroll
  for (int c = 0; c < 2; ++c){
    int g = c * 256 + t; int d = g >> 3, n8 = g & 7;
    short8 v;
    #pragma unroll
    for (int j = 0; j < 8; ++j) v[j] = tile[d * 66 + n8 * 8 + j];
    *(short8*)&XpT[(b * ND + d0 + d) * NN + n0 + n8 * 8] = v;
  }
}

// ---------------- K2: Y[b][h] = Xp @ attn_h  (bf16 out), MFMA vs attnT ------------
__global__ __launch_bounds__(256) void k2_y(const short* __restrict__ Xp,
                                            const short* __restrict__ attnT,
                                            short* __restrict__ Y){
  int bid = blockIdx.x;                       // 512 = 4b * 4h * 32
  int it = bid & 31, h = (bid >> 5) & 3, b = bid >> 7;
  int i0 = it << 6;
  int t = threadIdx.x, w = t >> 6, lane = t & 63, lq = lane >> 4, lc = lane & 15;
  __shared__ __align__(16) short ldsB[16384]; // swizzled [16 dblk][128 e][8]
  const short* Bsrc = attnT + h * 16384;
  #pragma unroll
  for (int c = 0; c < 8; ++c){
    int q = c * 256 + t; int dblk = q >> 7; int e = q & 127;
    *(short8*)&ldsB[q * 8] = *(const short8*)&Bsrc[e * 128 + dblk * 8];
  }
  short8 af[4][4];
  #pragma unroll
  for (int ib = 0; ib < 4; ++ib)
    #pragma unroll
    for (int k = 0; k < 4; ++k)
      af[ib][k] = *(const short8*)&Xp[(b * NN + i0 + ib * 16 + lc) * ND + k * 32 + lq * 8];
  __syncthreads();
  floatx4 acc[4][2];
  #pragma unroll
  for (int ib = 0; ib < 4; ++ib)
    #pragma unroll
    for (int eb = 0; eb < 2; ++eb) acc[ib][eb] = (floatx4){0.f, 0.f, 0.f, 0.f};
  #pragma unroll
  for (int eb = 0; eb < 2; ++eb)
    #pragma unroll
    for (int k = 0; k < 4; ++k){
      short8 bf = *(short8*)&ldsB[(k * 4 + lq) * 1024 + (w * 32 + eb * 16 + lc) * 8];
      #pragma unroll
      for (int ib = 0; ib < 4; ++ib)
        acc[ib][eb] = __builtin_amdgcn_mfma_f32_16x16x32_bf16(af[ib][k], bf, acc[ib][eb], 0, 0, 0);
    }
  #pragma unroll
  for (int ib = 0; ib < 4; ++ib)
    #pragma unroll
    for (int eb = 0; eb < 2; ++eb){
      int e = w * 32 + eb * 16 + lc;
      #pragma unroll
      for (int r = 0; r < 4; ++r){
        int n = i0 + ib * 16 + lq * 4 + r;
        Y[((b * NH + h) * NN + n) * ND + e] = f2bf(acc[ib][eb][r]);
      }
    }
}

// ---------------- K3 v4: barrier-free fused kernel (spill fix) --------------------
// Same structure as v3 (per-wave S^T -> tanh -> in-register PV via the K=16 MFMA
// A-frag identity; no main-loop barriers). v3 spilled: __launch_bounds__(256,4)
// capped regs at 128/wave; unified-file split (64 arch + 64 acc AGPR) left the
// ~100 live arch VGPRs short by ~40 -> WRITE_SIZE 90MB of scratch traffic.
// Fix: (256,3) -> ~170 reg budget, 3 blocks/CU (12 waves). Occupancy was never
// the binding constraint; spills were.
__global__ __launch_bounds__(256, 3) void k3_fused(const short* __restrict__ Xp,
                                                   const short* __restrict__ XpT,
                                                   const short* __restrict__ Y,
                                                   const float* __restrict__ A,
                                                   float* __restrict__ part){
  int bid = blockIdx.x;
  int it = bid & 127, b = (bid >> 7) & 3, ms = bid >> 9;
  int i0 = it << 4;
  int t = threadIdx.x, w = t >> 6, lane = t & 63, lq = lane >> 4, lc = lane & 15;

  // 32KB: ldsY (16KB, swizzled bf16) during the loop; red (32KB f32) at epilogue.
  __shared__ __align__(16) char smem[32768];

  // stage Y[b][4h][i0..i0+16][128] -> LDS, XOR-swizzle 16B slot with (i&7)
  #pragma unroll
  for (int c = 0; c < 4; ++c){
    int slot = c * 256 + t;
    int h = slot >> 8, i = (slot >> 4) & 15, d8 = slot & 15;
    short8 v = *(const short8*)&Y[((b * NH + h) * NN + i0 + i) * ND + d8 * 8];
    *(short8*)(smem + h * 4096 + i * 256 + ((d8 ^ (i & 7)) << 4)) = v;
  }
  __syncthreads();                            // the only pre-epilogue barrier

  floatx4 acc[8];                             // acc[dt] = part[i=lq*4+r][d=dt*16+lc]
  #pragma unroll
  for (int dt = 0; dt < 8; ++dt) acc[dt] = (floatx4){0.f,0.f,0.f,0.f};

  const int mbase = ms << 9;                  // 512 m per block, 128 per wave
  const float* arow = &A[(size_t)(b * NN + i0 + lc) * NN];

  // adjacency prefetch for itn=0 (this wave's 16 m-rows at row i0+lc)
  floatx4 av = *(const floatx4*)&arow[mbase + w * 16 + lq * 4];

  for (int itn = 0; itn < 8; ++itn){
    int m0 = mbase + itn * 64 + w * 16;       // this wave's 16 m-rows

    // S^T A-frags: Xp rows m0..m0+15 (L2/L3-resident)
    short8 xpf[4];
    const short* xr = Xp + (b * NN + m0 + lc) * ND;
    #pragma unroll
    for (int k = 0; k < 4; ++k) xpf[k] = *(const short8*)&xr[k * 32 + lq * 8];

    // PV B-frags: XpT[d][m0..m0+15], lane holds B[k=lq*4+j][col=d=dt*16+lc] (8B)
    short4v xt[8];
    #pragma unroll
    for (int dt = 0; dt < 8; ++dt)
      xt[dt] = *(const short4v*)&XpT[(size_t)(b * ND + dt * 16 + lc) * NN + m0 + lq * 4];

    // next-iter adjacency (HBM ~900cy, hides under S^T+tanh+PV; never drained)
    floatx4 avn = av;
    if (itn < 7) avn = *(const floatx4*)&arow[m0 + 64 + lq * 4];

    // S^T per head (Y B-frags from swizzled LDS), tanh, head-mean in-register
    float psum[4] = {0.f, 0.f, 0.f, 0.f};
    #pragma unroll
    for (int h = 0; h < 4; ++h){
      floatx4 S = (floatx4){0.f,0.f,0.f,0.f};
      #pragma unroll
      for (int k = 0; k < 4; ++k){
        short8 yf = *(short8*)(smem + h * 4096 + lc * 256 + (((k * 4 + lq) ^ (lc & 7)) << 4));
        S = __builtin_amdgcn_mfma_f32_16x16x32_bf16(xpf[k], yf, S, 0, 0, 0);
      }
      #pragma unroll
      for (int r = 0; r < 4; ++r){
        float x = av[r] * S[r];
        float e = __builtin_amdgcn_exp2f(x * 2.885390081777926f);  // e^{2x}
        psum[r] += 1.f - 2.f * __builtin_amdgcn_rcpf(e + 1.f);     // tanh
      }
    }

    // P -> bf16 hi/lo split; p[r] IS the K=16 A-frag element j=r directly
    short4v hi4, lo4;
    #pragma unroll
    for (int r = 0; r < 4; ++r){
      float pb = 0.25f * psum[r];
      short h16 = f2bf(pb);
      hi4[r] = h16;
      lo4[r] = f2bf(pb - bf2f(h16));
    }

    // PV: acc[dt] += (Phi + Plo) @ Xp over this wave's 16 m (K=16 MFMA, in-register)
    #pragma unroll
    for (int dt = 0; dt < 8; ++dt){
      acc[dt] = __builtin_amdgcn_mfma_f32_16x16x16bf16_1k(hi4, xt[dt], acc[dt], 0, 0, 0);
      acc[dt] = __builtin_amdgcn_mfma_f32_16x16x16bf16_1k(lo4, xt[dt], acc[dt], 0, 0, 0);
    }
    av = avn;
  }

  // epilogue: cross-wave sum via LDS (overlay red on ldsY region), single pass
  __syncthreads();                            // all waves done reading ldsY
  float* red = (float*)smem;                  // red[w][i][d] = w*2048 + i*128 + d
  #pragma unroll
  for (int dt = 0; dt < 8; ++dt)
    #pragma unroll
    for (int r = 0; r < 4; ++r)
      red[w * 2048 + (lq * 4 + r) * 128 + dt * 16 + lc] = acc[dt][r];
  __syncthreads();
  float* dst = part + (size_t)ms * 1048576 + (size_t)(b * NN + i0) * ND;
  #pragma unroll
  for (int j = 0; j < 8; ++j){
    int idx = j * 256 + t;                    // idx = i*128 + d, coalesced
    dst[idx] = red[idx] + red[2048 + idx] + red[4096 + idx] + red[6144 + idx];
  }
}

// ---------------- K4: out = relu(relu(Σ ms-partials) + X) -------------------------
__global__ void k4_final(const float* __restrict__ part, const float* __restrict__ X,
                         float* __restrict__ out){
  int f = (blockIdx.x * 256 + threadIdx.x) * 4;
  float4 s0 = *(const float4*)(part + f);
  float4 s1 = *(const float4*)(part + 1048576 + f);
  float4 s2 = *(const float4*)(part + 2097152 + f);
  float4 s3 = *(const float4*)(part + 3145728 + f);
  float4 xv = *(const float4*)(X + f);
  float4 o;
  o.x = fmaxf(fmaxf(s0.x + s1.x + s2.x + s3.x, 0.f) + xv.x, 0.f);
  o.y = fmaxf(fmaxf(s0.y + s1.y + s2.y + s3.y, 0.f) + xv.y, 0.f);
  o.z = fmaxf(fmaxf(s0.z + s1.z + s2.z + s3.z, 0.f) + xv.z, 0.f);
  o.w = fmaxf(fmaxf(s0.w + s1.w + s2.w + s3.w, 0.f) + xv.w, 0.f);
  *(float4*)(out + f) = o;
}

// ---------------- launch ----------------------------------------------------------
extern "C" void kernel_launch(void* const* d_in, const int* in_sizes, int n_in,
                              void* d_out, int out_size, void* d_ws, size_t ws_size,
                              hipStream_t stream) {
  const float* X    = (const float*)d_in[0];   // [4,2048,128]
  const float* A    = (const float*)d_in[1];   // [4,2048,2048]
  const float* W    = (const float*)d_in[2];   // [128,128]
  const float* bias = (const float*)d_in[3];   // [128]
  const float* attn = (const float*)d_in[4];   // [4,128,128]
  float* out = (float*)d_out;

  // workspace layout
  const size_t OFF_XP    = 0;                          // 2 MB bf16
  const size_t OFF_XPT   = (size_t)2 << 20;            // 2 MB bf16
  const size_t OFF_Y     = (size_t)4 << 20;            // 8 MB bf16
  const size_t OFF_PART  = (size_t)12 << 20;           // 16 MB f32 (4 partials)
  const size_t OFF_WT    = (size_t)28 << 20;           // 32 KB bf16
  const size_t OFF_ATTNT = OFF_WT + 32768;             // 128 KB bf16
  const size_t NEED = OFF_ATTNT + 131072;
  if (ws_size < NEED) return;

  char* ws = (char*)d_ws;
  short* Xp    = (short*)(ws + OFF_XP);
  short* XpT   = (short*)(ws + OFF_XPT);
  short* Y     = (short*)(ws + OFF_Y);
  float* part  = (float*)(ws + OFF_PART);
  short* WT    = (short*)(ws + OFF_WT);
  short* attnT = (short*)(ws + OFF_ATTNT);

  k0_transpose<<<5, 256, 0, stream>>>(W, attn, WT, attnT);
  k1_xp<<<128, 256, 0, stream>>>(X, WT, bias, Xp);
  k1b_transpose<<<256, 256, 0, stream>>>(Xp, XpT);
  k2_y<<<512, 256, 0, stream>>>(Xp, attnT, Y);
  k3_fused<<<2048, 256, 0, stream>>>(Xp, XpT, Y, A, part);
  k4_final<<<1024, 256, 0, stream>>>(part, X, out);
}